// Round 5
// baseline (2044.670 us; speedup 1.0000x reference)
//
#include <hip/hip_runtime.h>
#include <hip/hip_fp16.h>

typedef _Float16 half8 __attribute__((ext_vector_type(8)));
typedef _Float16 half4 __attribute__((ext_vector_type(4)));
typedef float floatx4 __attribute__((ext_vector_type(4)));

#define NB 32
#define NS 256
#define NSE 1024
#define ND 512
#define NV 8000
#define NVP 8064
#define NL 4
#define NH 8
#define NDK 64
#define KVB 128
#define BN_EPS 1e-3f

// ---- async global->LDS, 16B per lane (dest = wave-uniform base + lane*16) ----
typedef const __attribute__((address_space(1))) void* gas_ptr;
typedef __attribute__((address_space(3))) void* las_ptr;
__device__ __forceinline__ void gload16(const void* g, void* l) {
    __builtin_amdgcn_global_load_lds((gas_ptr)g, (las_ptr)l, 16, 0, 0);
}

// ---------------- fp32 -> fp16 cast (8 elems/thread) ----------------
__global__ __launch_bounds__(256) void k_cast(const float* __restrict__ in, _Float16* __restrict__ out) {
    size_t i = ((size_t)blockIdx.x * 256 + threadIdx.x) * 8;
    float4 a = *(const float4*)(in + i);
    float4 b = *(const float4*)(in + i + 4);
    half8 o;
    o[0] = (_Float16)a.x; o[1] = (_Float16)a.y; o[2] = (_Float16)a.z; o[3] = (_Float16)a.w;
    o[4] = (_Float16)b.x; o[5] = (_Float16)b.y; o[6] = (_Float16)b.z; o[7] = (_Float16)b.w;
    *(half8*)(out + i) = o;
}

// ---------------- embedding + positional (fp32 in, fp16 out) ----------------
__global__ __launch_bounds__(256) void k_embed(const int* __restrict__ seq,
                                               const float* __restrict__ emb,
                                               const float* __restrict__ pos,
                                               _Float16* __restrict__ x) {
    size_t i = ((size_t)blockIdx.x * 256 + threadIdx.x) * 8;
    int tok = (int)(i / ND);
    int d = (int)(i % ND);
    int s = tok % NS;
    int t = seq[tok];
    const float* ep = emb + (size_t)t * ND + d;
    const float* pp = pos + (size_t)s * ND + d;
    half8 o;
    for (int j = 0; j < 8; j++) o[j] = (_Float16)(ep[j] + pp[j]);
    *(half8*)(x + i) = o;
}

// ------------- weight transpose + cast: fp32 [R][C] -> fp16 [C][R] -------------
__global__ void k_transpose_w(const float* __restrict__ in, _Float16* __restrict__ out, int R, int C,
                              long long ostride) {
    __shared__ float tile[32][33];
    int b = blockIdx.z;
    int c0 = blockIdx.x * 32, r0 = blockIdx.y * 32;
    const float* pin = in + (size_t)b * R * C;
    _Float16* pout = out + (size_t)b * ostride;
    int tx = threadIdx.x, ty = threadIdx.y;                  // block (32,8)
    for (int j = 0; j < 32; j += 8)
        tile[ty + j][tx] = pin[(size_t)(r0 + ty + j) * C + c0 + tx];
    __syncthreads();
    for (int j = 0; j < 32; j += 8)
        pout[(size_t)(c0 + ty + j) * R + r0 + tx] = (_Float16)tile[tx][ty + j];
}

// ---- batched 512x512 transpose: ten weight groups x NL layers in one launch ----
struct TWArgs {
    const float* src[10];
    _Float16* dst[10];
    long long ostride[10];
};
__global__ void k_transpose_all(TWArgs a) {
    __shared__ float tile[32][33];
    int z = blockIdx.z;                  // 0..39
    int g = z >> 2, l = z & 3;
    const float* pin = a.src[g] + (size_t)l * ND * ND;
    _Float16* pout = a.dst[g] + (size_t)l * a.ostride[g];
    int c0 = blockIdx.x * 32, r0 = blockIdx.y * 32;
    int tx = threadIdx.x, ty = threadIdx.y;                  // block (32,8)
    for (int j = 0; j < 32; j += 8)
        tile[ty + j][tx] = pin[(size_t)(r0 + ty + j) * ND + c0 + tx];
    __syncthreads();
    for (int j = 0; j < 32; j += 8)
        pout[(size_t)(c0 + ty + j) * ND + r0 + tx] = (_Float16)tile[tx][ty + j];
}

// ---------------- fp16 MFMA GEMM: C[M,N] = A[M,K] @ Bt[N,K]^T + bias ----------
// BM x 128 tile, 256 thr = 4 waves (2x2), BK=64. 2-phase double-buffered K-loop
// (prefetch next tile, counted vmcnt, raw s_barrier) + T2 XOR-swizzled LDS.
// mode: 0 = fp16 row-major (width 512) into C0
//       1 = fp16 per-batch transposed [b][col][Sb] into C0 (BM=128 only: LDS-
//           transposed coalesced epilogue; requires Sb%128==0)
//       2 = fp32 row-major width N (vocab, guard col<N) into C0
//       3 = fp16 row-major width 512, out = BN(xres + gemm) into C0
//       4 = fused QKV: seg(n0/512) 0->C0, 1->C1, 2->C2(mode1,Sb)
//       5 = fused KV : seg 0->C0, 1->C1(mode1,Sb)
template<int BM>
__global__ __launch_bounds__(256) void k_gemm(
    const _Float16* __restrict__ A, const _Float16* __restrict__ Bt,
    const float* __restrict__ bias0, const float* __restrict__ bias1, const float* __restrict__ bias2,
    void* __restrict__ C0, void* __restrict__ C1, void* __restrict__ C2,
    int M, int N, int K, int relu, int mode, int Sb,
    const _Float16* __restrict__ xres,
    const float* __restrict__ bng, const float* __restrict__ bnb,
    const float* __restrict__ bnm, const float* __restrict__ bnv) {
    constexpr int BN = 128;
    constexpr int BK = 64;
    constexpr int MI = BM / 32;                 // A-frags per wave
    constexpr int BUFH = (BM + BN) * BK;        // halfs per buffer
    constexpr int LA = (BM + BN) / 32;          // gload16 issues per lane per tile
    __shared__ __align__(16) _Float16 smem[2 * BUFH];

    int tid = threadIdx.x;
    int wid = tid >> 6, lane = tid & 63, quad = lane >> 4, r = lane & 15;

    // bijective XCD-aware swizzle
    int nwg = gridDim.x * gridDim.y;
    int orig = blockIdx.y * gridDim.x + blockIdx.x;
    int q8 = nwg >> 3, r8 = nwg & 7;
    int xcd = orig & 7, loc = orig >> 3;
    int swz = (xcd < r8 ? xcd * (q8 + 1) : r8 * (q8 + 1) + (xcd - r8) * q8) + loc;
    int m0 = (swz / gridDim.x) * BM;
    int n0 = (swz % gridDim.x) * BN;

    int wm = (wid >> 1) * (BM / 2);             // wave tile rows
    int wn = (wid & 1) * 64;

    floatx4 zf = {0.f, 0.f, 0.f, 0.f};
    floatx4 acc[MI][4];
    for (int i = 0; i < MI; i++) for (int j = 0; j < 4; j++) acc[i][j] = zf;

    // staging: 8 lanes/row (16B chunks); T2: source chunk pre-swizzled by row&7
    int srow = wid * 8 + (lane >> 3);
    int scol = (((lane & 7) ^ ((lane >> 3) & 7)) << 3);

    auto stage = [&](int k0, int buf) {
        _Float16* As = smem + buf * BUFH;
        _Float16* Bs = As + BM * BK;
        const _Float16* abase = A + (size_t)(m0 + srow) * K + k0 + scol;
        _Float16* asl = As + (wid * 8) * BK;
#pragma unroll
        for (int i = 0; i < BM / 32; i++)
            gload16(abase + (size_t)(i * 32) * K, asl + (i * 32) * BK);
        const _Float16* bbase = Bt + (size_t)(n0 + srow) * K + k0 + scol;
        _Float16* bsl = Bs + (wid * 8) * BK;
#pragma unroll
        for (int i = 0; i < 4; i++)
            gload16(bbase + (size_t)(i * 32) * K, bsl + (i * 32) * BK);
    };

    int NT = K / BK;
    int cur = 0;
    stage(0, 0);
    for (int t = 0; t < NT; t++) {
        if (t + 1 < NT) {
            stage((t + 1) * BK, cur ^ 1);
            asm volatile("s_waitcnt vmcnt(%0)" :: "n"(LA) : "memory");
        } else {
            asm volatile("s_waitcnt vmcnt(0)" ::: "memory");
        }
        __builtin_amdgcn_s_barrier();           // current tile ready in LDS
        const _Float16* As = smem + cur * BUFH;
        const _Float16* Bs = As + BM * BK;
#pragma unroll
        for (int ks = 0; ks < BK; ks += 32) {
            half8 af[MI], bg[4];
#pragma unroll
            for (int i = 0; i < MI; i++)
                af[i] = *(const half8*)&As[(wm + i * 16 + r) * BK + ((((ks >> 3) + quad) ^ (r & 7)) << 3)];
#pragma unroll
            for (int j = 0; j < 4; j++)
                bg[j] = *(const half8*)&Bs[(wn + j * 16 + r) * BK + ((((ks >> 3) + quad) ^ (r & 7)) << 3)];
#pragma unroll
            for (int i = 0; i < MI; i++)
#pragma unroll
                for (int j = 0; j < 4; j++)
                    acc[i][j] = __builtin_amdgcn_mfma_f32_16x16x32_f16(af[i], bg[j], acc[i][j], 0, 0, 0);
        }
        if (t + 1 < NT) {
            __builtin_amdgcn_s_barrier();       // all reads of buf done before re-stage
            cur ^= 1;
        }
    }

    // ---- resolve output routing (per-block uniform: BN=128 divides 512) ----
    int seg = 0, nloc = n0, om = mode;
    const float* bias = bias0;
    char* C = (char*)C0;
    if (mode == 4) {
        seg = n0 >> 9; nloc = n0 & 511;
        om = (seg == 2) ? 1 : 0;
        C = (char*)(seg == 0 ? C0 : (seg == 1 ? C1 : C2));
        bias = (seg == 0) ? bias0 : ((seg == 1) ? bias1 : bias2);
    } else if (mode == 5) {
        seg = n0 >> 9; nloc = n0 & 511;
        om = seg ? 1 : 0;
        C = (char*)(seg ? C1 : C0);
        bias = seg ? bias1 : bias0;
    }

    if (om == 1) {
        if constexpr (BM == 128) {
            // stage [col][s] tile in the free LDS buffer (exactly BUFH halfs),
            // XOR-swizzled on 8B chunks, then coalesced half8 stores along s.
            _Float16* Lt = smem + (cur ^ 1) * BUFH;     // 128 cols x 128 s
            for (int i = 0; i < MI; i++) {
                int sl = wm + i * 16 + quad * 4;
                int cs = sl >> 2;                        // 8B chunk idx 0..31
#pragma unroll
                for (int j = 0; j < 4; j++) {
                    int cl = wn + j * 16 + r;
                    float bv = bias[nloc + cl];
                    half4 h;
#pragma unroll
                    for (int g = 0; g < 4; g++) h[g] = (_Float16)(acc[i][j][g] + bv);
                    *(half4*)&Lt[cl * BM + ((cs ^ (cl & 7)) << 2)] = h;
                }
            }
            __syncthreads();
            int b = m0 / Sb, s0 = m0 - b * Sb;           // 128 rows stay in one batch
            _Float16* outb = (_Float16*)C + (size_t)b * 512 * Sb + s0;
            int tcol = tid >> 4;                         // 0..15
            int ts8 = (tid & 15) * 8;
            int cs0 = ts8 >> 2;
#pragma unroll
            for (int p = 0; p < 8; p++) {
                int cl = p * 16 + tcol;
                half4 lo = *(const half4*)&Lt[cl * BM + ((cs0 ^ (cl & 7)) << 2)];
                half4 hi = *(const half4*)&Lt[cl * BM + (((cs0 + 1) ^ (cl & 7)) << 2)];
                half8 o;
                o[0] = lo[0]; o[1] = lo[1]; o[2] = lo[2]; o[3] = lo[3];
                o[4] = hi[0]; o[5] = hi[1]; o[6] = hi[2]; o[7] = hi[3];
                *(half8*)&outb[(size_t)(nloc + cl) * Sb + ts8] = o;
            }
        } else {
            // fallback scalar path (unused in current launches)
            for (int i = 0; i < MI; i++) {
                int grow = m0 + wm + i * 16 + quad * 4;
                int b = grow / Sb, s = grow - b * Sb;
                _Float16* outp = (_Float16*)C + (size_t)b * 512 * Sb + s;
#pragma unroll
                for (int j = 0; j < 4; j++) {
                    int cb = nloc + wn + j * 16 + r;
                    float bv = bias[cb];
                    half4 h;
#pragma unroll
                    for (int g = 0; g < 4; g++) h[g] = (_Float16)(acc[i][j][g] + bv);
                    *(half4*)(outp + (size_t)cb * Sb) = h;
                }
            }
        }
    } else {
        // per-wave fp32 staging tile [16][68] in the FREE double-buffer half
        float* Ep = (float*)(void*)(smem + (cur ^ 1) * BUFH) + wid * (16 * 68);
        int rr = lane >> 4;
        int c = (lane & 15) * 4;
        for (int i = 0; i < MI; i++) {
#pragma unroll
            for (int j = 0; j < 4; j++) {
                int cb = nloc + wn + j * 16 + r;
                float bv = (om == 2) ? (cb < N ? bias[cb] : 0.0f) : bias[cb];
#pragma unroll
                for (int g = 0; g < 4; g++) {
                    float v = acc[i][j][g] + bv;
                    if (relu) v = fmaxf(v, 0.0f);
                    Ep[(quad * 4 + g) * 68 + j * 16 + r] = v;
                }
            }
            int grow0 = m0 + wm + i * 16;
            int cb = nloc + wn + c;
            if (om == 0) {
#pragma unroll
                for (int p = 0; p < 4; p++) {
                    float4 v = *(float4*)&Ep[(p * 4 + rr) * 68 + c];
                    half4 h;
                    h[0] = (_Float16)v.x; h[1] = (_Float16)v.y; h[2] = (_Float16)v.z; h[3] = (_Float16)v.w;
                    *(half4*)&((_Float16*)C)[(size_t)(grow0 + p * 4 + rr) * 512 + cb] = h;
                }
            } else if (om == 3) {
                float4 g4 = *(const float4*)(bng + cb);
                float4 b4 = *(const float4*)(bnb + cb);
                float4 m4 = *(const float4*)(bnm + cb);
                float4 v4 = *(const float4*)(bnv + cb);
                float s0 = g4.x * rsqrtf(v4.x + BN_EPS);
                float s1 = g4.y * rsqrtf(v4.y + BN_EPS);
                float s2 = g4.z * rsqrtf(v4.z + BN_EPS);
                float s3 = g4.w * rsqrtf(v4.w + BN_EPS);
#pragma unroll
                for (int p = 0; p < 4; p++) {
                    int grow = grow0 + p * 4 + rr;
                    float4 v = *(float4*)&Ep[(p * 4 + rr) * 68 + c];
                    half4 xv = *(const half4*)(xres + (size_t)grow * 512 + cb);
                    half4 h;
                    h[0] = (_Float16)((v.x + (float)xv[0] - m4.x) * s0 + b4.x);
                    h[1] = (_Float16)((v.y + (float)xv[1] - m4.y) * s1 + b4.y);
                    h[2] = (_Float16)((v.z + (float)xv[2] - m4.z) * s2 + b4.z);
                    h[3] = (_Float16)((v.w + (float)xv[3] - m4.w) * s3 + b4.w);
                    *(half4*)&((_Float16*)C)[(size_t)grow * 512 + cb] = h;
                }
            } else {            // om == 2: fp32 row-major width N
                if (cb < N) {
#pragma unroll
                    for (int p = 0; p < 4; p++) {
                        float4 v = *(float4*)&Ep[(p * 4 + rr) * 68 + c];
                        *(float4*)&((float*)C)[(size_t)(grow0 + p * 4 + rr) * N + cb] = v;
                    }
                }
            }
        }
    }
}

// ---------------- fused flash attention (fp16 in/out, fp32 softmax) ----------------
// KVB=128 keys per iteration: halves per-key softmax fixed costs and barriers.
__global__ __launch_bounds__(256) void k_attn(const _Float16* __restrict__ Q, const _Float16* __restrict__ Kb,
                                              const _Float16* __restrict__ Vt, _Float16* __restrict__ O,
                                              int Sk, int causal) {
    __shared__ _Float16 Plds[4][16][KVB + 8];
    int qt = blockIdx.x, h = blockIdx.y, b = blockIdx.z;
    int tid = threadIdx.x;
    int w = tid >> 6, lane = tid & 63, quad = lane >> 4, r = lane & 15;
    int qbase = qt * 64 + w * 16;

    floatx4 zf = {0.f, 0.f, 0.f, 0.f};
    half8 aq[2];
    const _Float16* qptr = Q + (size_t)(b * NS + qbase + r) * ND + h * NDK;
    aq[0] = *(const half8*)(qptr + quad * 8);
    aq[1] = *(const half8*)(qptr + 32 + quad * 8);

    floatx4 Of[4];
    for (int j = 0; j < 4; j++) Of[j] = zf;
    float mrow[4], lrow[4];
    for (int g = 0; g < 4; g++) { mrow[g] = -1e30f; lrow[g] = 0.0f; }

    int ntiles = causal ? ((qt * 64 + 63) / KVB + 1) : (Sk / KVB);

    for (int kt = 0; kt < ntiles; kt++) {
        floatx4 sc[8];
#pragma unroll
        for (int j = 0; j < 8; j++) sc[j] = zf;
        __builtin_amdgcn_s_setprio(1);
#pragma unroll
        for (int t = 0; t < 2; t++) {
#pragma unroll
            for (int j = 0; j < 8; j++) {
                const _Float16* kptr = Kb + (size_t)(b * Sk + kt * KVB + j * 16 + r) * ND + h * NDK + t * 32 + quad * 8;
                half8 bk = *(const half8*)kptr;
                sc[j] = __builtin_amdgcn_mfma_f32_16x16x32_f16(aq[t], bk, sc[j], 0, 0, 0);
            }
        }
        __builtin_amdgcn_s_setprio(0);
        float s[8][4], tmax[4];
#pragma unroll
        for (int g = 0; g < 4; g++) tmax[g] = -1e30f;
#pragma unroll
        for (int j = 0; j < 8; j++) {
            int key = kt * KVB + j * 16 + r;
#pragma unroll
            for (int g = 0; g < 4; g++) {
                float v = sc[j][g] * 0.125f;                 // 1/sqrt(64)
                int qi = qbase + quad * 4 + g;
                if (causal && key >= qi) v = -1e30f;
                s[j][g] = v;
                tmax[g] = fmaxf(tmax[g], v);
            }
        }
#pragma unroll
        for (int off = 1; off < 16; off <<= 1)
#pragma unroll
            for (int g = 0; g < 4; g++)
                tmax[g] = fmaxf(tmax[g], __shfl_xor(tmax[g], off, 64));
        float alpha[4], psum[4];
#pragma unroll
        for (int g = 0; g < 4; g++) {
            float mnew = fmaxf(mrow[g], tmax[g]);
            alpha[g] = (mnew <= -1e29f) ? 1.0f : __expf(mrow[g] - mnew);
            mrow[g] = mnew;
            psum[g] = 0.0f;
        }
#pragma unroll
        for (int j = 0; j < 8; j++) {
#pragma unroll
            for (int g = 0; g < 4; g++) {
                float p = (s[j][g] <= -1e29f) ? 0.0f : __expf(s[j][g] - mrow[g]);
                psum[g] += p;
                Plds[w][quad * 4 + g][j * 16 + r] = (_Float16)p;
            }
        }
#pragma unroll
        for (int off = 1; off < 16; off <<= 1)
#pragma unroll
            for (int g = 0; g < 4; g++)
                psum[g] += __shfl_xor(psum[g], off, 64);
#pragma unroll
        for (int g = 0; g < 4; g++) lrow[g] = lrow[g] * alpha[g] + psum[g];
#pragma unroll
        for (int j = 0; j < 4; j++)
#pragma unroll
            for (int g = 0; g < 4; g++)
                Of[j][g] *= alpha[g];
        __syncthreads();   // P writes visible before frag reads
        __builtin_amdgcn_s_setprio(1);
#pragma unroll
        for (int t = 0; t < 4; t++) {
            half8 ap = *(const half8*)&Plds[w][r][t * 32 + quad * 8];
#pragma unroll
            for (int j = 0; j < 4; j++) {
                const _Float16* vptr = Vt + (size_t)((b * NH + h) * NDK + j * 16 + r) * Sk + kt * KVB + t * 32 + quad * 8;
                half8 bv = *(const half8*)vptr;
                Of[j] = __builtin_amdgcn_mfma_f32_16x16x32_f16(ap, bv, Of[j], 0, 0, 0);
            }
        }
        __builtin_amdgcn_s_setprio(0);
        __syncthreads();
    }
    for (int j = 0; j < 4; j++) {
        for (int g = 0; g < 4; g++) {
            int row = qbase + quad * 4 + g;
            float inv = (lrow[g] > 0.f) ? 1.0f / lrow[g] : 0.0f;
            O[(size_t)(b * NS + row) * ND + h * NDK + j * 16 + r] = (_Float16)(Of[j][g] * inv);
        }
    }
}

extern "C" void kernel_launch(void* const* d_in, const int* in_sizes, int n_in,
                              void* d_out, int out_size, void* d_ws, size_t ws_size,
                              hipStream_t stream) {
    const int*   seq  = (const int*)d_in[0];
    const float* enc  = (const float*)d_in[1];
    const float* pos  = (const float*)d_in[2];
    const float* emb  = (const float*)d_in[3];
    const float* Wout = (const float*)d_in[4];
    const float* bout = (const float*)d_in[5];
    const float* W1   = (const float*)d_in[6];
    const float* b1   = (const float*)d_in[7];
    const float* W2   = (const float*)d_in[8];
    const float* b2   = (const float*)d_in[9];
    const float* Wq_bot = (const float*)d_in[10];
    const float* Wk_bot = (const float*)d_in[11];
    const float* Wv_bot = (const float*)d_in[12];
    const float* Wo_bot = (const float*)d_in[13];
    const float* bq_bot = (const float*)d_in[14];
    const float* bk_bot = (const float*)d_in[15];
    const float* bv_bot = (const float*)d_in[16];
    const float* bo_bot = (const float*)d_in[17];
    const float* Wq_mid = (const float*)d_in[18];
    const float* Wk_mid = (const float*)d_in[19];
    const float* Wv_mid = (const float*)d_in[20];
    const float* Wo_mid = (const float*)d_in[21];
    const float* bq_mid = (const float*)d_in[22];
    const float* bk_mid = (const float*)d_in[23];
    const float* bv_mid = (const float*)d_in[24];
    const float* bo_mid = (const float*)d_in[25];
    const float* gam[3] = {(const float*)d_in[26], (const float*)d_in[30], (const float*)d_in[34]};
    const float* bet[3] = {(const float*)d_in[27], (const float*)d_in[31], (const float*)d_in[35]};
    const float* mea[3] = {(const float*)d_in[28], (const float*)d_in[32], (const float*)d_in[36]};
    const float* vr [3] = {(const float*)d_in[29], (const float*)d_in[33], (const float*)d_in[37]};

    char* wp = (char*)d_ws;
    auto alloc = [&](size_t elems) -> _Float16* {
        _Float16* p = (_Float16*)wp;
        wp += ((elems * 2 + 255) / 256) * 256;
        return p;
    };
    const size_t DD = (size_t)ND * ND;
    _Float16* WqkvTb = alloc(NL * 3 * DD);      // [l][1536][512]: Wq^T,Wk^T,Wv^T
    _Float16* WoTb   = alloc(NL * DD);
    _Float16* WqTm   = alloc(NL * DD);
    _Float16* WkvTm  = alloc(NL * 2 * DD);      // [l][1024][512]: Wk^T,Wv^T
    _Float16* WoTm   = alloc(NL * DD);
    _Float16* W1T    = alloc(NL * DD);
    _Float16* W2T    = alloc(NL * DD);
    _Float16* WoutT  = alloc((size_t)NVP * ND);
    const size_t XSZ = (size_t)NB * NS * ND;
    _Float16* x   = alloc(XSZ);
    _Float16* qb  = alloc(XSZ);
    _Float16* kb  = alloc(XSZ);
    _Float16* vts = alloc(XSZ);                 // V^T self  [B,512,S]
    _Float16* ao  = alloc(XSZ);
    const size_t ESZ = (size_t)NB * NSE * ND;
    _Float16* ench  = alloc(ESZ);
    _Float16* kenc  = alloc(ESZ);
    _Float16* vtenc = alloc(ESZ);               // V^T cross [B,512,SE]

    // zero WoutT's padded tail rows (guard-free staging in the vocab GEMM)
    hipMemsetAsync(WoutT + (size_t)NV * ND, 0, (size_t)(NVP - NV) * ND * sizeof(_Float16), stream);

    dim3 tb(32, 8);
    const long long S1 = (long long)DD, S2 = (long long)(2 * DD), S3 = (long long)(3 * DD);
    TWArgs ta;
    ta.src[0] = Wq_bot; ta.dst[0] = WqkvTb;          ta.ostride[0] = S3;
    ta.src[1] = Wk_bot; ta.dst[1] = WqkvTb + DD;     ta.ostride[1] = S3;
    ta.src[2] = Wv_bot; ta.dst[2] = WqkvTb + 2 * DD; ta.ostride[2] = S3;
    ta.src[3] = Wo_bot; ta.dst[3] = WoTb;            ta.ostride[3] = S1;
    ta.src[4] = Wq_mid; ta.dst[4] = WqTm;            ta.ostride[4] = S1;
    ta.src[5] = Wk_mid; ta.dst[5] = WkvTm;           ta.ostride[5] = S2;
    ta.src[6] = Wv_mid; ta.dst[6] = WkvTm + DD;      ta.ostride[6] = S2;
    ta.src[7] = Wo_mid; ta.dst[7] = WoTm;            ta.ostride[7] = S1;
    ta.src[8] = W1;     ta.dst[8] = W1T;             ta.ostride[8] = S1;
    ta.src[9] = W2;     ta.dst[9] = W2T;             ta.ostride[9] = S1;
    k_transpose_all<<<dim3(16, 16, 40), tb, 0, stream>>>(ta);
    k_transpose_w<<<dim3(NV / 32, 16, 1), tb, 0, stream>>>(Wout, WoutT, ND, NV, S1);
    k_cast<<<dim3((int)(ESZ / 8 / 256)), 256, 0, stream>>>(enc, ench);
    k_embed<<<dim3((int)(XSZ / 8 / 256)), 256, 0, stream>>>(seq, emb, pos, x);

    // N=512 GEMM, M=8192, BM=64: grid (4,128) = 512 blocks
    auto gemm64 = [&](const _Float16* A, const _Float16* Bt, const float* b0, void* Cp,
                      int relu, int mode, const _Float16* xr, const float* g, const float* be,
                      const float* me, const float* ve) {
        k_gemm<64><<<dim3(4, 128), 256, 0, stream>>>(A, Bt, b0, nullptr, nullptr,
            Cp, nullptr, nullptr, 8192, 512, 512, relu, mode, 0, xr, g, be, me, ve);
    };

    for (int l = 0; l < NL; l++) {
        size_t wofs = (size_t)l * DD;
        size_t bofs = (size_t)l * ND;
        // --- causal self-attention: fused QKV projection (N=1536) ---
        k_gemm<128><<<dim3(12, 64), 256, 0, stream>>>(x, WqkvTb + (size_t)l * 3 * DD,
            bq_bot + bofs, bk_bot + bofs, bv_bot + bofs, qb, kb, vts,
            8192, 1536, 512, 0, 4, NS, nullptr, nullptr, nullptr, nullptr, nullptr);
        k_attn<<<dim3(NS / 64, NH, NB), 256, 0, stream>>>(qb, kb, vts, ao, NS, 1);
        gemm64(ao, WoTb + wofs, bo_bot + bofs, x, 0, 3, x,
               gam[0] + bofs, bet[0] + bofs, mea[0] + bofs, vr[0] + bofs);
        // --- cross-attention: Q proj + fused KV-encoder projection (N=1024) ---
        gemm64(x, WqTm + wofs, bq_mid + bofs, qb, 0, 0, nullptr, nullptr, nullptr, nullptr, nullptr);
        k_gemm<128><<<dim3(8, 256), 256, 0, stream>>>(ench, WkvTm + (size_t)l * 2 * DD,
            bk_mid + bofs, bv_mid + bofs, nullptr, kenc, vtenc, nullptr,
            32768, 1024, 512, 0, 5, NSE, nullptr, nullptr, nullptr, nullptr, nullptr);
        k_attn<<<dim3(NS / 64, NH, NB), 256, 0, stream>>>(qb, kenc, vtenc, ao, NSE, 0);
        gemm64(ao, WoTm + wofs, bo_mid + bofs, x, 0, 3, x,
               gam[1] + bofs, bet[1] + bofs, mea[1] + bofs, vr[1] + bofs);
        // --- FFN ---
        gemm64(x, W1T + wofs, b1 + bofs, qb, 1, 0, nullptr, nullptr, nullptr, nullptr, nullptr);
        gemm64(qb, W2T + wofs, b2 + bofs, x, 0, 3, x,
               gam[2] + bofs, bet[2] + bofs, mea[2] + bofs, vr[2] + bofs);
    }
    // --- final vocab projection, fp32 straight to d_out ---
    k_gemm<128><<<dim3(63, 64), 256, 0, stream>>>(x, WoutT, bout, nullptr, nullptr,
        d_out, nullptr, nullptr, 8192, NV, 512, 0, 2, 0, nullptr, nullptr, nullptr, nullptr, nullptr);
}